// Round 7
// baseline (762.089 us; speedup 1.0000x reference)
//
#include <hip/hip_runtime.h>
#include <hip/hip_bf16.h>

#define NN 50000     // nodes
#define NE 600000    // edges
#define NF 11        // raw features
#define DD 128       // hidden dim
#define NB 500       // graphs
#define MA 100       // max atoms per graph
#define NLAY 5       // conv layers
#define NBLK ((NN + 255) / 256)   // 196 scan blocks

static __device__ __forceinline__ float bflo(unsigned u) {
    return __uint_as_float(u << 16);
}
static __device__ __forceinline__ float bfhi(unsigned u) {
    return __uint_as_float(u & 0xffff0000u);
}

// --- zero an int region ----------------------------------------------------
__global__ __launch_bounds__(256) void k_zero(int* __restrict__ p, int n) {
    int i = blockIdx.x * 256 + threadIdx.x;
    if (i < n) p[i] = 0;
}

// --- expansion: xb = bf16( log(atoms+1) @ W_exp + b_exp ) ------------------
__global__ __launch_bounds__(256) void k_expand(
        const float* __restrict__ atoms,
        const float* __restrict__ W_exp,
        const float* __restrict__ b_exp,
        __hip_bfloat16* __restrict__ xb) {
    int sub  = threadIdx.x >> 7;            // 2 nodes per block
    int node = blockIdx.x * 2 + sub;
    int d    = threadIdx.x & 127;
    __shared__ float la[2][NF];
    if (node < NN && d < NF)
        la[sub][d] = logf(atoms[node * NF + d] + 1.0f);
    __syncthreads();
    if (node >= NN) return;
    float acc = b_exp[d];
#pragma unroll
    for (int f = 0; f < NF; ++f)
        acc = fmaf(la[sub][f], W_exp[f * DD + d], acc);
    xb[(size_t)node * DD + d] = __float2bfloat16(acc);
}

// --- degree count ----------------------------------------------------------
__global__ __launch_bounds__(256) void k_count(const int* __restrict__ col,
                                               int* __restrict__ cnt) {
    int e = blockIdx.x * 256 + threadIdx.x;
    if (e < NE) atomicAdd(cnt + col[e], 1);
}

// --- dinv / self_norm ------------------------------------------------------
__global__ __launch_bounds__(256) void k_dinv(const int* __restrict__ cnt,
                                              float* __restrict__ dinv,
                                              float* __restrict__ selfn) {
    int n = blockIdx.x * 256 + threadIdx.x;
    if (n < NN) {
        float r = 1.0f / sqrtf((float)cnt[n] + 2.0f);
        dinv[n]  = r;
        selfn[n] = 2.0f * r * r;
    }
}

// --- hierarchical exclusive scan: cnt -> ptrb ------------------------------
__global__ __launch_bounds__(256) void k_scan1(const int* __restrict__ cnt,
                                               int* __restrict__ ptrb,
                                               int* __restrict__ bsum) {
    __shared__ int s[256];
    int t = threadIdx.x;
    int i = blockIdx.x * 256 + t;
    int v = (i < NN) ? cnt[i] : 0;
    s[t] = v;
    __syncthreads();
    for (int off = 1; off < 256; off <<= 1) {
        int tv = (t >= off) ? s[t - off] : 0;
        __syncthreads();
        s[t] += tv;
        __syncthreads();
    }
    if (i < NN) ptrb[i] = s[t] - v;
    if (t == 255) bsum[blockIdx.x] = s[255];
}

__global__ __launch_bounds__(256) void k_scan2(const int* __restrict__ bsum,
                                               int* __restrict__ boff,
                                               int* __restrict__ ptr_last) {
    __shared__ int s[256];
    int t = threadIdx.x;
    int v = (t < NBLK) ? bsum[t] : 0;
    s[t] = v;
    __syncthreads();
    for (int off = 1; off < 256; off <<= 1) {
        int tv = (t >= off) ? s[t - off] : 0;
        __syncthreads();
        s[t] += tv;
        __syncthreads();
    }
    if (t < NBLK) boff[t] = s[t] - v;
    if (t == 255) *ptr_last = s[255];   // total == NE
}

__global__ __launch_bounds__(256) void k_scan3(int* __restrict__ ptrb,
                                               const int* __restrict__ boff) {
    int i = blockIdx.x * 256 + threadIdx.x;
    if (i < NN) ptrb[i] += boff[blockIdx.x];
}

// --- scatter edges into CSR (sorted by target), packed (src, w) ------------
__global__ __launch_bounds__(256) void k_scatter(
        const int* __restrict__ conn, const int* __restrict__ ptrb,
        int* __restrict__ cursor, const float* __restrict__ dinv,
        int2* __restrict__ epack) {
    int e = blockIdx.x * 256 + threadIdx.x;
    if (e < NE) {
        int r = conn[e];
        int c = conn[NE + e];
        int p = ptrb[c] + atomicAdd(cursor + c, 1);
        int2 rec; rec.x = r; rec.y = __float_as_int(dinv[r] * dinv[c]);
        epack[p] = rec;
    }
}

// --- per-graph counts / scan -----------------------------------------------
__global__ __launch_bounds__(256) void k_gcount(const int* __restrict__ batch,
                                                int* __restrict__ gcnt) {
    int n = blockIdx.x * 256 + threadIdx.x;
    if (n < NN) atomicAdd(gcnt + batch[n], 1);
}

__global__ __launch_bounds__(512) void k_gscan(const int* __restrict__ gcnt,
                                               int* __restrict__ gptr) {
    __shared__ int s[512];
    int t = threadIdx.x;
    int v = (t < NB) ? gcnt[t] : 0;
    s[t] = v;
    __syncthreads();
    for (int off = 1; off < 512; off <<= 1) {
        int tv = (t >= off) ? s[t - off] : 0;
        __syncthreads();
        s[t] += tv;
        __syncthreads();
    }
    if (t < NB) gptr[t] = s[t] - v;
}

// --- fused layer: relu( (P xb) @ W + b ) -----------------------------------
// 8 nodes/block, 256 threads, LDS = 4KB y tile. Gather: 2 nodes/wave,
// edge loop unrolled x4 (4 packed-edge loads then 4 row gathers in flight).
// GEMM: thread = (node, 4 cols); W from global (L1/L2 broadcast);
// yt reads are same-address LDS broadcasts (free).
__global__ __launch_bounds__(256) void k_layer(
        const __hip_bfloat16* __restrict__ xb, const int* __restrict__ ptrb,
        const int2* __restrict__ ep, const float* __restrict__ selfn,
        const float* __restrict__ W, const float* __restrict__ bias,
        __hip_bfloat16* __restrict__ xob,
        int last, const int* __restrict__ batch, const int* __restrict__ gptr,
        float* __restrict__ out) {
    __shared__ float yt[8 * DD];   // 4 KB
    int tid  = threadIdx.x;
    int wave = tid >> 6, lane = tid & 63;
    int nodebase = blockIdx.x * 8;

    // phase 1: gather y rows (2 nodes per wave), bf16 source, f32 accum
    const unsigned* xq = (const unsigned*)xb;   // 2 bf16 per word
#pragma unroll
    for (int i = 0; i < 2; ++i) {
        int node = nodebase + wave * 2 + i;
        int p0 = ptrb[node], p1 = ptrb[node + 1];
        float sn = selfn[node];
        unsigned u = xq[(size_t)node * 64 + lane];
        float a0 = bflo(u) * sn, a1 = bfhi(u) * sn;
        int p = p0;
        for (; p + 4 <= p1; p += 4) {
            int2 e0 = ep[p], e1 = ep[p + 1], e2 = ep[p + 2], e3 = ep[p + 3];
            unsigned v0 = xq[(size_t)e0.x * 64 + lane];
            unsigned v1 = xq[(size_t)e1.x * 64 + lane];
            unsigned v2 = xq[(size_t)e2.x * 64 + lane];
            unsigned v3 = xq[(size_t)e3.x * 64 + lane];
            float w0 = __int_as_float(e0.y), w1 = __int_as_float(e1.y);
            float w2 = __int_as_float(e2.y), w3 = __int_as_float(e3.y);
            a0 = fmaf(bflo(v0), w0, a0); a1 = fmaf(bfhi(v0), w0, a1);
            a0 = fmaf(bflo(v1), w1, a0); a1 = fmaf(bfhi(v1), w1, a1);
            a0 = fmaf(bflo(v2), w2, a0); a1 = fmaf(bfhi(v2), w2, a1);
            a0 = fmaf(bflo(v3), w3, a0); a1 = fmaf(bfhi(v3), w3, a1);
        }
        for (; p < p1; ++p) {
            int2 e = ep[p];
            unsigned v = xq[(size_t)e.x * 64 + lane];
            float w = __int_as_float(e.y);
            a0 = fmaf(bflo(v), w, a0); a1 = fmaf(bfhi(v), w, a1);
        }
        float2 o; o.x = a0; o.y = a1;
        *(float2*)&yt[(wave * 2 + i) * DD + lane * 2] = o;
    }
    __syncthreads();

    // phase 2: GEMM + bias + relu (thread = node n, cols d0..d0+3)
    int dg = tid & 31;  int d0 = dg * 4;
    int n  = tid >> 5;
    const float4* W4 = (const float4*)W;
    const float4* yn = (const float4*)&yt[n * DD];
    float ax = 0, ay = 0, az = 0, aw = 0;
#pragma unroll 4
    for (int kk = 0; kk < 32; ++kk) {
        float4 ya = yn[kk];
        float4 w0 = W4[(kk * 4 + 0) * 32 + dg];
        float4 w1 = W4[(kk * 4 + 1) * 32 + dg];
        float4 w2 = W4[(kk * 4 + 2) * 32 + dg];
        float4 w3 = W4[(kk * 4 + 3) * 32 + dg];
        ax = fmaf(w0.x, ya.x, ax); ay = fmaf(w0.y, ya.x, ay);
        az = fmaf(w0.z, ya.x, az); aw = fmaf(w0.w, ya.x, aw);
        ax = fmaf(w1.x, ya.y, ax); ay = fmaf(w1.y, ya.y, ay);
        az = fmaf(w1.z, ya.y, az); aw = fmaf(w1.w, ya.y, aw);
        ax = fmaf(w2.x, ya.z, ax); ay = fmaf(w2.y, ya.z, ay);
        az = fmaf(w2.z, ya.z, az); aw = fmaf(w2.w, ya.z, aw);
        ax = fmaf(w3.x, ya.w, ax); ay = fmaf(w3.y, ya.w, ay);
        az = fmaf(w3.z, ya.w, az); aw = fmaf(w3.w, ya.w, aw);
    }
    float4 bv = ((const float4*)bias)[dg];
    float ox = fmaxf(ax + bv.x, 0.0f), oy = fmaxf(ay + bv.y, 0.0f);
    float oz = fmaxf(az + bv.z, 0.0f), ow = fmaxf(aw + bv.w, 0.0f);

    int node = nodebase + n;
    if (!last) {
        ushort4 pk;
        pk.x = __bfloat16_as_ushort(__float2bfloat16(ox));
        pk.y = __bfloat16_as_ushort(__float2bfloat16(oy));
        pk.z = __bfloat16_as_ushort(__float2bfloat16(oz));
        pk.w = __bfloat16_as_ushort(__float2bfloat16(ow));
        *(ushort4*)((unsigned short*)xob + (size_t)node * DD + d0) = pk;
    } else {
        int b  = batch[node];
        int ix = b * MA + (node - gptr[b]);
        float4 o4; o4.x = ox; o4.y = oy; o4.z = oz; o4.w = ow;
        *(float4*)&out[(size_t)ix * DD + d0] = o4;
        if (dg == 0)
            out[(size_t)NB * MA * DD + ix] = 1.0f;
    }
}

extern "C" void kernel_launch(void* const* d_in, const int* in_sizes, int n_in,
                              void* d_out, int out_size, void* d_ws, size_t ws_size,
                              hipStream_t stream) {
    const float* atoms = (const float*)d_in[0];
    const int*   conn  = (const int*)d_in[1];
    const int*   batch = (const int*)d_in[2];
    const float* W_exp = (const float*)d_in[3];
    const float* b_exp = (const float*)d_in[4];
    const float* Ws    = (const float*)d_in[5];
    const float* bs    = (const float*)d_in[6];
    float* out = (float*)d_out;   // reference output dtype is float32

    char* ws = (char*)d_ws;
    size_t off = 0;
    auto nextbuf = [&](size_t bytes) {
        void* p = ws + off;
        off = (off + bytes + 255) & ~(size_t)255;
        return p;
    };
    __hip_bfloat16* xb0 = (__hip_bfloat16*)nextbuf((size_t)NN * DD * 2);
    __hip_bfloat16* xb1 = (__hip_bfloat16*)nextbuf((size_t)NN * DD * 2);
    int*   izero = (int*)  nextbuf((size_t)(2 * NN + NB) * 4);  // cnt|cursor|gcnt
    int*   cnt    = izero;
    int*   cursor = izero + NN;
    int*   gcnt   = izero + 2 * NN;
    int*   ptrb  = (int*)  nextbuf((size_t)(NN + 1) * 4);
    float* dinv  = (float*)nextbuf((size_t)NN * 4);
    float* selfn = (float*)nextbuf((size_t)NN * 4);
    int2*  epack = (int2*) nextbuf((size_t)NE * 8);
    int*   gptr  = (int*)  nextbuf((size_t)NB * 4);
    int*   bsum  = (int*)  nextbuf((size_t)NBLK * 4);
    int*   boff  = (int*)  nextbuf((size_t)NBLK * 4);
    (void)ws_size; (void)n_in; (void)in_sizes; (void)out_size;

    const int NZ = 2 * NN + NB;
    k_zero   <<<(NZ + 255) / 256,    256, 0, stream>>>(izero, NZ);
    k_expand <<<NN / 2,              256, 0, stream>>>(atoms, W_exp, b_exp, xb0);
    k_count  <<<(NE + 255) / 256,    256, 0, stream>>>(conn + NE, cnt);
    k_dinv   <<<(NN + 255) / 256,    256, 0, stream>>>(cnt, dinv, selfn);
    k_scan1  <<<NBLK,                256, 0, stream>>>(cnt, ptrb, bsum);
    k_scan2  <<<1,                   256, 0, stream>>>(bsum, boff, ptrb + NN);
    k_scan3  <<<NBLK,                256, 0, stream>>>(ptrb, boff);
    k_scatter<<<(NE + 255) / 256,    256, 0, stream>>>(conn, ptrb, cursor, dinv, epack);
    k_gcount <<<(NN + 255) / 256,    256, 0, stream>>>(batch, gcnt);
    k_gscan  <<<1,                   512, 0, stream>>>(gcnt, gptr);

    __hip_bfloat16* xa = xb0;
    __hip_bfloat16* xb = xb1;
    for (int l = 0; l < NLAY; ++l) {
        int last = (l == NLAY - 1);
        k_layer<<<NN / 8, 256, 0, stream>>>(xa, ptrb, epack, selfn,
                                            Ws + (size_t)l * DD * DD,
                                            bs + (size_t)l * DD,
                                            xb, last, batch, gptr, out);
        __hip_bfloat16* t = xa; xa = xb; xb = t;
    }
}

// Round 10
// 553.328 us; speedup vs baseline: 1.3773x; 1.3773x over previous
//
#include <hip/hip_runtime.h>
#include <hip/hip_bf16.h>

#define NN 50000     // nodes
#define NE 600000    // edges
#define NF 11        // raw features
#define DD 128       // hidden dim
#define NB 500       // graphs
#define MA 100       // max atoms per graph
#define NLAY 5       // conv layers
#define NBLK ((NN + 255) / 256)   // 196 scan blocks

typedef __attribute__((ext_vector_type(8))) short short8v;   // 8 bf16 (4 VGPR)
typedef __attribute__((ext_vector_type(4))) float float4v;

static __device__ __forceinline__ unsigned short f2bu(float f) {
    return __bfloat16_as_ushort(__float2bfloat16(f));
}

// --- zero an int region ----------------------------------------------------
__global__ __launch_bounds__(256) void k_zero(int* __restrict__ p, int n) {
    int i = blockIdx.x * 256 + threadIdx.x;
    if (i < n) p[i] = 0;
}

// --- W prep: transposed split bf16 (truncation hi + RNE lo) ----------------
// Wt_hi[n][k] + Wt_lo[n][k] ~= W[k][n]  (error ~2^-17 |w|)
__global__ __launch_bounds__(256) void k_wprep(const float* __restrict__ Ws,
                                               unsigned short* __restrict__ Wth,
                                               unsigned short* __restrict__ Wtl) {
    int idx = blockIdx.x * 256 + threadIdx.x;
    if (idx >= NLAY * DD * DD) return;
    int l   = idx / (DD * DD);
    int rem = idx - l * (DD * DD);
    int k   = rem >> 7, n = rem & 127;          // read coalesced in n
    float w = Ws[idx];
    unsigned hb = __float_as_uint(w) & 0xffff0000u;   // exact bf16 (truncate)
    float r = w - __uint_as_float(hb);                // exact in f32
    Wth[(size_t)l * DD * DD + n * DD + k] = (unsigned short)(hb >> 16);
    Wtl[(size_t)l * DD * DD + n * DD + k] = f2bu(r);
}

// --- expansion: x = log(atoms+1) @ W_exp + b_exp (f32 out) -----------------
__global__ __launch_bounds__(256) void k_expand(
        const float* __restrict__ atoms,
        const float* __restrict__ W_exp,
        const float* __restrict__ b_exp,
        float* __restrict__ x) {
    int sub  = threadIdx.x >> 7;            // 2 nodes per block
    int node = blockIdx.x * 2 + sub;
    int d    = threadIdx.x & 127;
    __shared__ float la[2][NF];
    if (node < NN && d < NF)
        la[sub][d] = logf(atoms[node * NF + d] + 1.0f);
    __syncthreads();
    if (node >= NN) return;
    float acc = b_exp[d];
#pragma unroll
    for (int f = 0; f < NF; ++f)
        acc = fmaf(la[sub][f], W_exp[f * DD + d], acc);
    x[(size_t)node * DD + d] = acc;
}

// --- degree count ----------------------------------------------------------
__global__ __launch_bounds__(256) void k_count(const int* __restrict__ col,
                                               int* __restrict__ cnt) {
    int e = blockIdx.x * 256 + threadIdx.x;
    if (e < NE) atomicAdd(cnt + col[e], 1);
}

// --- dinv / self_norm ------------------------------------------------------
__global__ __launch_bounds__(256) void k_dinv(const int* __restrict__ cnt,
                                              float* __restrict__ dinv,
                                              float* __restrict__ selfn) {
    int n = blockIdx.x * 256 + threadIdx.x;
    if (n < NN) {
        float r = 1.0f / sqrtf((float)cnt[n] + 2.0f);
        dinv[n]  = r;
        selfn[n] = 2.0f * r * r;
    }
}

// --- hierarchical exclusive scan: cnt -> ptrb ------------------------------
__global__ __launch_bounds__(256) void k_scan1(const int* __restrict__ cnt,
                                               int* __restrict__ ptrb,
                                               int* __restrict__ bsum) {
    __shared__ int s[256];
    int t = threadIdx.x;
    int i = blockIdx.x * 256 + t;
    int v = (i < NN) ? cnt[i] : 0;
    s[t] = v;
    __syncthreads();
    for (int off = 1; off < 256; off <<= 1) {
        int tv = (t >= off) ? s[t - off] : 0;
        __syncthreads();
        s[t] += tv;
        __syncthreads();
    }
    if (i < NN) ptrb[i] = s[t] - v;
    if (t == 255) bsum[blockIdx.x] = s[255];
}

__global__ __launch_bounds__(256) void k_scan2(const int* __restrict__ bsum,
                                               int* __restrict__ boff,
                                               int* __restrict__ ptr_last) {
    __shared__ int s[256];
    int t = threadIdx.x;
    int v = (t < NBLK) ? bsum[t] : 0;
    s[t] = v;
    __syncthreads();
    for (int off = 1; off < 256; off <<= 1) {
        int tv = (t >= off) ? s[t - off] : 0;
        __syncthreads();
        s[t] += tv;
        __syncthreads();
    }
    if (t < NBLK) boff[t] = s[t] - v;
    if (t == 255) *ptr_last = s[255];   // total == NE
}

__global__ __launch_bounds__(256) void k_scan3(int* __restrict__ ptrb,
                                               const int* __restrict__ boff) {
    int i = blockIdx.x * 256 + threadIdx.x;
    if (i < NN) ptrb[i] += boff[blockIdx.x];
}

// --- scatter edges into CSR (sorted by target), packed (src, w) ------------
__global__ __launch_bounds__(256) void k_scatter(
        const int* __restrict__ conn, const int* __restrict__ ptrb,
        int* __restrict__ cursor, const float* __restrict__ dinv,
        int2* __restrict__ epack) {
    int e = blockIdx.x * 256 + threadIdx.x;
    if (e < NE) {
        int r = conn[e];
        int c = conn[NE + e];
        int p = ptrb[c] + atomicAdd(cursor + c, 1);
        int2 rec; rec.x = r; rec.y = __float_as_int(dinv[r] * dinv[c]);
        epack[p] = rec;
    }
}

// --- per-graph counts / scan -----------------------------------------------
__global__ __launch_bounds__(256) void k_gcount(const int* __restrict__ batch,
                                                int* __restrict__ gcnt) {
    int n = blockIdx.x * 256 + threadIdx.x;
    if (n < NN) atomicAdd(gcnt + batch[n], 1);
}

__global__ __launch_bounds__(512) void k_gscan(const int* __restrict__ gcnt,
                                               int* __restrict__ gptr) {
    __shared__ int s[512];
    int t = threadIdx.x;
    int v = (t < NB) ? gcnt[t] : 0;
    s[t] = v;
    __syncthreads();
    for (int off = 1; off < 512; off <<= 1) {
        int tv = (t >= off) ? s[t - off] : 0;
        __syncthreads();
        s[t] += tv;
        __syncthreads();
    }
    if (t < NB) gptr[t] = s[t] - v;
}

// --- fused layer: relu( (P x) @ W + b ), f32 x, split-bf16 MFMA GEMM -------
// 16 nodes/block, 256 threads, LDS = 8KB (y split hi/lo, XOR-swizzled 16B).
// Phase 1: wave gathers 4 node-rows from f32 x (float2/lane, unroll x4),
//          splits each f32 into exact-truncated bf16 hi + RNE bf16 lo.
// Phase 2: 32x mfma_f32_16x16x32_bf16: (ah+al)(bh+bl) all 4 terms ->
//          f32-exact GEMM to ~2^-17.
__global__ __launch_bounds__(256) void k_layer(
        const float* __restrict__ x, const int* __restrict__ ptrb,
        const int2* __restrict__ ep, const float* __restrict__ selfn,
        const unsigned short* __restrict__ Wth,
        const unsigned short* __restrict__ Wtl,
        const float* __restrict__ bias,
        float* __restrict__ xo,
        int last, const int* __restrict__ batch, const int* __restrict__ gptr,
        float* __restrict__ out) {
    __shared__ __align__(16) unsigned ylh[16 * 64];   // y_hi, swizzled
    __shared__ __align__(16) unsigned yll[16 * 64];   // y_lo, swizzled
    int tid  = threadIdx.x;
    int wave = tid >> 6, lane = tid & 63;
    int nodebase = blockIdx.x * 16;

    // phase 1: gather y rows (4 nodes per wave) from f32 x
    const float2* x2 = (const float2*)x;
#pragma unroll
    for (int i = 0; i < 4; ++i) {
        int row  = wave * 4 + i;
        int node = nodebase + row;
        int p0 = ptrb[node], p1 = ptrb[node + 1];
        float sn = selfn[node];
        float2 u = x2[(size_t)node * 64 + lane];
        float a0 = u.x * sn, a1 = u.y * sn;
        int p = p0;
        for (; p + 4 <= p1; p += 4) {
            int2 e0 = ep[p], e1 = ep[p + 1], e2 = ep[p + 2], e3 = ep[p + 3];
            float2 v0 = x2[(size_t)e0.x * 64 + lane];
            float2 v1 = x2[(size_t)e1.x * 64 + lane];
            float2 v2 = x2[(size_t)e2.x * 64 + lane];
            float2 v3 = x2[(size_t)e3.x * 64 + lane];
            float w0 = __int_as_float(e0.y), w1 = __int_as_float(e1.y);
            float w2 = __int_as_float(e2.y), w3 = __int_as_float(e3.y);
            a0 = fmaf(v0.x, w0, a0); a1 = fmaf(v0.y, w0, a1);
            a0 = fmaf(v1.x, w1, a0); a1 = fmaf(v1.y, w1, a1);
            a0 = fmaf(v2.x, w2, a0); a1 = fmaf(v2.y, w2, a1);
            a0 = fmaf(v3.x, w3, a0); a1 = fmaf(v3.y, w3, a1);
        }
        for (; p < p1; ++p) {
            int2 e = ep[p];
            float2 v = x2[(size_t)e.x * 64 + lane];
            float w = __int_as_float(e.y);
            a0 = fmaf(v.x, w, a0); a1 = fmaf(v.y, w, a1);
        }
        // exact truncation split: hi = top16 bits (exact), lo = RNE(residual)
        unsigned hb0 = __float_as_uint(a0) & 0xffff0000u;
        unsigned hb1 = __float_as_uint(a1) & 0xffff0000u;
        unsigned short l0 = f2bu(a0 - __uint_as_float(hb0));
        unsigned short l1 = f2bu(a1 - __uint_as_float(hb1));
        int widx = row * 64 + ((lane >> 2) ^ row) * 4 + (lane & 3);
        ylh[widx] = (hb0 >> 16) | (hb1 & 0xffff0000u);
        yll[widx] = (unsigned)l0 | ((unsigned)l1 << 16);
    }
    __syncthreads();

    // phase 2: 32x MFMA. A-frag row = lane&15, k0 = kb*32 + (lane>>4)*8.
    // B-frag col = wave*32 + nt*16 + (lane&15), same k0 (L2-hot global).
    float4v acc0 = {0.f, 0.f, 0.f, 0.f};
    float4v acc1 = {0.f, 0.f, 0.f, 0.f};
    const short8v* WTH8 = (const short8v*)Wth;
    const short8v* WTL8 = (const short8v*)Wtl;
    int arow = lane & 15;
    int n0c = wave * 32 + (lane & 15);        // nt=0 column
#pragma unroll
    for (int kb = 0; kb < 4; ++kb) {
        int chunk = (kb * 4 + (lane >> 4)) ^ arow;
        short8v ah = *(const short8v*)&ylh[arow * 64 + chunk * 4];
        short8v al = *(const short8v*)&yll[arow * 64 + chunk * 4];
        int bidx = kb * 4 + (lane >> 4);
        short8v bh0 = WTH8[n0c * 16 + bidx];
        short8v bl0 = WTL8[n0c * 16 + bidx];
        short8v bh1 = WTH8[(n0c + 16) * 16 + bidx];
        short8v bl1 = WTL8[(n0c + 16) * 16 + bidx];
        acc0 = __builtin_amdgcn_mfma_f32_16x16x32_bf16(ah, bh0, acc0, 0, 0, 0);
        acc0 = __builtin_amdgcn_mfma_f32_16x16x32_bf16(al, bh0, acc0, 0, 0, 0);
        acc0 = __builtin_amdgcn_mfma_f32_16x16x32_bf16(ah, bl0, acc0, 0, 0, 0);
        acc0 = __builtin_amdgcn_mfma_f32_16x16x32_bf16(al, bl0, acc0, 0, 0, 0);
        acc1 = __builtin_amdgcn_mfma_f32_16x16x32_bf16(ah, bh1, acc1, 0, 0, 0);
        acc1 = __builtin_amdgcn_mfma_f32_16x16x32_bf16(al, bh1, acc1, 0, 0, 0);
        acc1 = __builtin_amdgcn_mfma_f32_16x16x32_bf16(ah, bl1, acc1, 0, 0, 0);
        acc1 = __builtin_amdgcn_mfma_f32_16x16x32_bf16(al, bl1, acc1, 0, 0, 0);
    }

    // epilogue: D col = lane&15, row = (lane>>4)*4 + reg
#pragma unroll
    for (int nt = 0; nt < 2; ++nt) {
        int d  = wave * 32 + nt * 16 + (lane & 15);
        float bv = bias[d];
#pragma unroll
        for (int r = 0; r < 4; ++r) {
            int row  = (lane >> 4) * 4 + r;
            int node = nodebase + row;
            float o = fmaxf((nt ? acc1[r] : acc0[r]) + bv, 0.0f);
            if (!last) {
                xo[(size_t)node * DD + d] = o;
            } else {
                int b  = batch[node];
                int ix = b * MA + (node - gptr[b]);
                out[(size_t)ix * DD + d] = o;
            }
        }
    }
    if (last && wave == 0 && (lane & 15) == 0) {
#pragma unroll
        for (int r = 0; r < 4; ++r) {
            int node = nodebase + (lane >> 4) * 4 + r;
            int b  = batch[node];
            int ix = b * MA + (node - gptr[b]);
            out[(size_t)NB * MA * DD + ix] = 1.0f;   // mask True
        }
    }
}

extern "C" void kernel_launch(void* const* d_in, const int* in_sizes, int n_in,
                              void* d_out, int out_size, void* d_ws, size_t ws_size,
                              hipStream_t stream) {
    const float* atoms = (const float*)d_in[0];
    const int*   conn  = (const int*)d_in[1];
    const int*   batch = (const int*)d_in[2];
    const float* W_exp = (const float*)d_in[3];
    const float* b_exp = (const float*)d_in[4];
    const float* Ws    = (const float*)d_in[5];
    const float* bs    = (const float*)d_in[6];
    float* out = (float*)d_out;   // reference output dtype is float32

    char* ws = (char*)d_ws;
    size_t off = 0;
    auto nextbuf = [&](size_t bytes) {
        void* p = ws + off;
        off = (off + bytes + 255) & ~(size_t)255;
        return p;
    };
    float* x0 = (float*)nextbuf((size_t)NN * DD * 4);
    float* x1 = (float*)nextbuf((size_t)NN * DD * 4);
    unsigned short* Wth = (unsigned short*)nextbuf((size_t)NLAY * DD * DD * 2);
    unsigned short* Wtl = (unsigned short*)nextbuf((size_t)NLAY * DD * DD * 2);
    int*   izero = (int*)  nextbuf((size_t)(2 * NN + NB) * 4);  // cnt|cursor|gcnt
    int*   cnt    = izero;
    int*   cursor = izero + NN;
    int*   gcnt   = izero + 2 * NN;
    int*   ptrb  = (int*)  nextbuf((size_t)(NN + 1) * 4);
    float* dinv  = (float*)nextbuf((size_t)NN * 4);
    float* selfn = (float*)nextbuf((size_t)NN * 4);
    int2*  epack = (int2*) nextbuf((size_t)NE * 8);
    int*   gptr  = (int*)  nextbuf((size_t)NB * 4);
    int*   bsum  = (int*)  nextbuf((size_t)NBLK * 4);
    int*   boff  = (int*)  nextbuf((size_t)NBLK * 4);
    (void)ws_size; (void)n_in; (void)in_sizes; (void)out_size;

    const int NZ = 2 * NN + NB;
    k_zero   <<<(NZ + 255) / 256,    256, 0, stream>>>(izero, NZ);
    k_wprep  <<<(NLAY * DD * DD + 255) / 256, 256, 0, stream>>>(Ws, Wth, Wtl);
    k_expand <<<NN / 2,              256, 0, stream>>>(atoms, W_exp, b_exp, x0);
    k_count  <<<(NE + 255) / 256,    256, 0, stream>>>(conn + NE, cnt);
    k_dinv   <<<(NN + 255) / 256,    256, 0, stream>>>(cnt, dinv, selfn);
    k_scan1  <<<NBLK,                256, 0, stream>>>(cnt, ptrb, bsum);
    k_scan2  <<<1,                   256, 0, stream>>>(bsum, boff, ptrb + NN);
    k_scan3  <<<NBLK,                256, 0, stream>>>(ptrb, boff);
    k_scatter<<<(NE + 255) / 256,    256, 0, stream>>>(conn, ptrb, cursor, dinv, epack);
    k_gcount <<<(NN + 255) / 256,    256, 0, stream>>>(batch, gcnt);
    k_gscan  <<<1,                   512, 0, stream>>>(gcnt, gptr);

    float* xa = x0;
    float* xc = x1;
    for (int l = 0; l < NLAY; ++l) {
        int last = (l == NLAY - 1);
        k_layer<<<NN / 16, 256, 0, stream>>>(xa, ptrb, epack, selfn,
                                             Wth + (size_t)l * DD * DD,
                                             Wtl + (size_t)l * DD * DD,
                                             bs + (size_t)l * DD,
                                             xc, last, batch, gptr, out);
        float* t = xa; xa = xc; xc = t;
    }
}